// Round 13
// baseline (567.889 us; speedup 1.0000x reference)
//
#include <hip/hip_runtime.h>

// ---------------------------------------------------------------------------
// GCN forward (R12 + radix two-pass CSR build):
//   build: 64-bucket histogram -> bucket scan -> pass1 (LDS-binned partition,
//          XCD-local bucket appends, fused deg count) -> node scan(+dinv) ->
//          pass2 (per-bucket scatter to final CSR, L2-window-local writes)
//   W prep: cast all 3 W to fp16 in MFMA B-fragment order
//   layer1: x(f32) @ W1 -> A16 ; agg -> H16 (relu'd fp16)
//   layer2: H16 @ W2 -> A16 ; agg -> H16
//   layer3: H16 @ W3 -> A16 ; head agg + lin_w dot -> nodeval -> segreduce
// ---------------------------------------------------------------------------

typedef __attribute__((ext_vector_type(4))) float f32x4;
typedef __attribute__((ext_vector_type(8))) _Float16 half8;

#define P1_EDGES 2048
#define P2_SUBS 32

// 64-bucket destination histogram (LDS-binned; 8 global partial copies)
__global__ __launch_bounds__(256) void hist_kernel(const int* __restrict__ col,
                                                   int* __restrict__ bucketCnt8,
                                                   int E, int npb) {
    __shared__ int lh[64];
    const int tid = threadIdx.x;
    const int base = blockIdx.x * P1_EDGES;
    if (tid < 64) lh[tid] = 0;
    __syncthreads();
    #pragma unroll
    for (int i = 0; i < 8; ++i) {
        int e = base + i * 256 + tid;
        if (e < E) atomicAdd(&lh[__builtin_nontemporal_load(&col[e]) / npb], 1);
    }
    __syncthreads();
    if (tid < 64 && lh[tid] > 0)
        atomicAdd(&bucketCnt8[((blockIdx.x & 7) << 6) + tid], lh[tid]);
}

// reduce 8 partial copies + exclusive scan -> bucketStart, bucketTail
__global__ __launch_bounds__(64) void bucketscan_kernel(const int* __restrict__ bucketCnt8,
                                                        int* __restrict__ bucketStart,
                                                        int* __restrict__ bucketTail) {
    __shared__ int ts[64];
    const int t = threadIdx.x;
    int s = 0;
    #pragma unroll
    for (int r = 0; r < 8; ++r) s += bucketCnt8[(r << 6) + t];
    ts[t] = s;
    __syncthreads();
    if (t == 0) {
        int acc = 0;
        for (int i = 0; i < 64; ++i) {
            bucketStart[i] = acc;
            bucketTail[i] = acc;
            acc += ts[i];
        }
    }
}

// pass 1: partition edges into 64 dest buckets (bucket k handled by XCD k&7).
// LDS-binned: per-block local offsets, 8 block-aggregated tail atomics, then
// dense appends near the 8 XCD-local tails. Also counts deg (replaces count_deg).
__global__ __launch_bounds__(256) void pass1_kernel(const int* __restrict__ ei,
                                                    int* __restrict__ deg,
                                                    int* __restrict__ bucketTail,
                                                    int2* __restrict__ tmp,
                                                    int E, int npb) {
    __shared__ int lcnt[8];
    __shared__ int lbase[8];
    const int p = blockIdx.x & 7;
    const int base = (blockIdx.x >> 3) * P1_EDGES;
    const int tid = threadIdx.x;
    if (tid < 8) lcnt[tid] = 0;
    __syncthreads();
    int myc[8], myr[8], myidx[8];
    #pragma unroll
    for (int i = 0; i < 8; ++i) {
        myidx[i] = -1;
        int e = base + i * 256 + tid;
        if (e < E) {
            int c = __builtin_nontemporal_load(&ei[E + e]);
            int k = c / npb;
            if ((k & 7) == p) {
                int r = __builtin_nontemporal_load(&ei[e]);
                atomicAdd(&deg[c], 1);
                int lk = k >> 3;
                int lp = atomicAdd(&lcnt[lk], 1);
                myc[i] = c; myr[i] = r;
                myidx[i] = (lk << 16) | lp;      // lp < 2048 fits in 16 bits
            }
        }
    }
    __syncthreads();
    if (tid < 8) lbase[tid] = atomicAdd(&bucketTail[(tid << 3) | p], lcnt[tid]);
    __syncthreads();
    #pragma unroll
    for (int i = 0; i < 8; ++i) {
        if (myidx[i] >= 0) {
            int lk = myidx[i] >> 16, lp = myidx[i] & 0xFFFF;
            tmp[lbase[lk] + lp] = make_int2(myr[i], myc[i]);
        }
    }
}

// per-block exclusive scan of deg (1024/block) -> rowptr; also dinv = rsqrt(deg+1)
__global__ __launch_bounds__(256) void scan1_kernel(const int* __restrict__ deg,
                                                    int* __restrict__ rowptr,
                                                    float* __restrict__ dinv,
                                                    int* __restrict__ blockSums, int N) {
    __shared__ int ts[256];
    const int t = threadIdx.x;
    const int base = blockIdx.x * 1024 + t * 4;
    int v0 = 0, v1 = 0, v2 = 0, v3 = 0;
    if (base + 3 < N) {
        int4 v = *(const int4*)&deg[base];
        v0 = v.x; v1 = v.y; v2 = v.z; v3 = v.w;
    } else {
        if (base + 0 < N) v0 = deg[base + 0];
        if (base + 1 < N) v1 = deg[base + 1];
        if (base + 2 < N) v2 = deg[base + 2];
        if (base + 3 < N) v3 = deg[base + 3];
    }
    if (base + 0 < N) dinv[base + 0] = 1.0f / sqrtf((float)v0 + 1.0f);
    if (base + 1 < N) dinv[base + 1] = 1.0f / sqrtf((float)v1 + 1.0f);
    if (base + 2 < N) dinv[base + 2] = 1.0f / sqrtf((float)v2 + 1.0f);
    if (base + 3 < N) dinv[base + 3] = 1.0f / sqrtf((float)v3 + 1.0f);
    const int tot = v0 + v1 + v2 + v3;
    ts[t] = tot;
    __syncthreads();
    for (int off = 1; off < 256; off <<= 1) {
        int add = (t >= off) ? ts[t - off] : 0;
        __syncthreads();
        ts[t] += add;
        __syncthreads();
    }
    const int excl = ts[t] - tot;
    if (base + 0 < N) rowptr[base + 0] = excl;
    if (base + 1 < N) rowptr[base + 1] = excl + v0;
    if (base + 2 < N) rowptr[base + 2] = excl + v0 + v1;
    if (base + 3 < N) rowptr[base + 3] = excl + v0 + v1 + v2;
    if (t == 255) blockSums[blockIdx.x] = ts[255];
}

__global__ __launch_bounds__(128) void scan2_kernel(const int* __restrict__ blockSums,
                                                    int* __restrict__ blockOffs, int B) {
    __shared__ int ts[128];
    const int t = threadIdx.x;
    ts[t] = (t < B) ? blockSums[t] : 0;
    __syncthreads();
    for (int off = 1; off < 128; off <<= 1) {
        int add = (t >= off) ? ts[t - off] : 0;
        __syncthreads();
        ts[t] += add;
        __syncthreads();
    }
    if (t < B) blockOffs[t] = ts[t];
}

// add block offsets; mirror result into nodeTail (pass2 working tails); rowptr[N]=E
__global__ __launch_bounds__(256) void scan3_kernel(int* __restrict__ rowptr,
                                                    int* __restrict__ nodeTail,
                                                    const int* __restrict__ blockOffs,
                                                    int N, int E) {
    int i = blockIdx.x * 256 + threadIdx.x;
    if (i == 0) rowptr[N] = E;
    if (i >= N) return;
    int b = i >> 10;
    int v = rowptr[i];
    if (b > 0) v += blockOffs[b - 1];
    rowptr[i] = v;
    nodeTail[i] = v;
}

// pass 2: per-bucket scatter to final CSR positions. Bucket k runs on XCD k&7;
// writes land in bucket k's contiguous ~200KB final range (fits L2 window).
__global__ __launch_bounds__(256) void pass2_kernel(const int2* __restrict__ tmp,
                                                    const int* __restrict__ bucketStart,
                                                    const int* __restrict__ bucketTail,
                                                    const float* __restrict__ dinv,
                                                    int* __restrict__ nodeTail,
                                                    int2* __restrict__ edges) {
    const int p = blockIdx.x & 7;
    const int j = blockIdx.x >> 3;
    const int k = ((j & 7) << 3) | p;
    const int sub = j >> 3;                       // 0..P2_SUBS-1
    const int lo = bucketStart[k];
    const int hi = bucketTail[k];
    const int chunk = (hi - lo + P2_SUBS - 1) / P2_SUBS;
    const int s = lo + sub * chunk;
    const int t = min(s + chunk, hi);
    for (int i = s + (int)threadIdx.x; i < t; i += 256) {
        int2 rc = tmp[i];
        int pos = atomicAdd(&nodeTail[rc.y], 1);
        edges[pos] = make_int2(rc.x, __float_as_int(dinv[rc.x]));
    }
}

// cast all three W[128][128] fp32 -> fp16 in MFMA B-fragment order:
// idx = ((c*8+t)*64+lane)*8+j <-> W[k][n], k=c*32+(lane>>4)*8+j, n=t*16+(lane&15)
__global__ __launch_bounds__(256) void wcast_kernel(const float* __restrict__ W1,
                                                    const float* __restrict__ W2,
                                                    const float* __restrict__ W3,
                                                    _Float16* __restrict__ W16) {
    int layer = blockIdx.x >> 6;
    const float* W = (layer == 0) ? W1 : (layer == 1) ? W2 : W3;
    _Float16* Wd = W16 + layer * 16384;
    int i = (blockIdx.x & 63) * 256 + threadIdx.x;
    int j = i & 7;
    int l = (i >> 3) & 63;
    int t = (i >> 9) & 7;
    int c = i >> 12;
    int k = c * 32 + (l >> 4) * 8 + j;
    int n = t * 16 + (l & 15);
    Wd[i] = (_Float16)W[k * 128 + n];
}

// A16 = fp16( x_f32 @ W16 ) via f16 MFMA (layer 1; cvt x in-register)
__global__ __launch_bounds__(256) void gemm_f32_kernel(const float* __restrict__ H,
                                                       const _Float16* __restrict__ W16,
                                                       _Float16* __restrict__ T16,
                                                       int N) {
    const int tid = threadIdx.x;
    const int wv = tid >> 6;
    const int lane = tid & 63;
    const int r0 = blockIdx.x * 64 + wv * 16;
    const int mrow = lane & 15;
    const int kq = lane >> 4;
    const int grow = r0 + mrow;
    const bool rok = grow < N;

    f32x4 acc[8];
    #pragma unroll
    for (int t = 0; t < 8; ++t) acc[t] = (f32x4){0.f, 0.f, 0.f, 0.f};

    #pragma unroll
    for (int c = 0; c < 4; ++c) {
        half8 a = (half8)(_Float16)0;
        if (rok) {
            const float4* Hp = (const float4*)(H + (size_t)grow * 128 + c * 32 + kq * 8);
            float4 a0 = Hp[0], a1 = Hp[1];
            a[0] = (_Float16)a0.x; a[1] = (_Float16)a0.y;
            a[2] = (_Float16)a0.z; a[3] = (_Float16)a0.w;
            a[4] = (_Float16)a1.x; a[5] = (_Float16)a1.y;
            a[6] = (_Float16)a1.z; a[7] = (_Float16)a1.w;
        }
        #pragma unroll
        for (int t = 0; t < 8; ++t) {
            half8 w = *(const half8*)&W16[(((c * 8 + t) * 64) + lane) * 8];
            acc[t] = __builtin_amdgcn_mfma_f32_16x16x32_f16(a, w, acc[t], 0, 0, 0);
        }
    }
    #pragma unroll
    for (int r = 0; r < 4; ++r) {
        int orow = r0 + kq * 4 + r;
        if (orow < N) {
            _Float16* Tp = T16 + (size_t)orow * 128 + mrow;
            #pragma unroll
            for (int t = 0; t < 8; ++t) Tp[t * 16] = (_Float16)acc[t][r];
        }
    }
}

// A16 = fp16( H16 @ W16 ) via f16 MFMA (layers 2/3)
__global__ __launch_bounds__(256) void gemm_f16_kernel(const _Float16* __restrict__ H16,
                                                       const _Float16* __restrict__ W16,
                                                       _Float16* __restrict__ T16,
                                                       int N) {
    const int tid = threadIdx.x;
    const int wv = tid >> 6;
    const int lane = tid & 63;
    const int r0 = blockIdx.x * 64 + wv * 16;
    const int mrow = lane & 15;
    const int kq = lane >> 4;
    const int grow = r0 + mrow;
    const bool rok = grow < N;

    f32x4 acc[8];
    #pragma unroll
    for (int t = 0; t < 8; ++t) acc[t] = (f32x4){0.f, 0.f, 0.f, 0.f};

    #pragma unroll
    for (int c = 0; c < 4; ++c) {
        half8 a = (half8)(_Float16)0;
        if (rok) a = *(const half8*)(H16 + (size_t)grow * 128 + c * 32 + kq * 8);
        #pragma unroll
        for (int t = 0; t < 8; ++t) {
            half8 w = *(const half8*)&W16[(((c * 8 + t) * 64) + lane) * 8];
            acc[t] = __builtin_amdgcn_mfma_f32_16x16x32_f16(a, w, acc[t], 0, 0, 0);
        }
    }
    #pragma unroll
    for (int r = 0; r < 4; ++r) {
        int orow = r0 + kq * 4 + r;
        if (orow < N) {
            _Float16* Tp = T16 + (size_t)orow * 128 + mrow;
            #pragma unroll
            for (int t = 0; t < 8; ++t) Tp[t * 16] = (_Float16)acc[t][r];
        }
    }
}

// one wave per node; 8 lanes/edge x 32B (2 x half8), 8 edges in flight.
// H16[n,:] = fp16(relu( dinv[n]^2*A[n,:] + bias + sum_e dn*w_e*A[src_e,:] ))
__global__ __launch_bounds__(256) void agg_kernel(const int* __restrict__ rowptr,
                                                  const int2* __restrict__ edges,
                                                  const float* __restrict__ dinv,
                                                  const _Float16* __restrict__ A16,
                                                  const float* __restrict__ bias,
                                                  _Float16* __restrict__ H16, int N) {
    int w = (blockIdx.x * 256 + threadIdx.x) >> 6;
    if (w >= N) return;
    const int lane = threadIdx.x & 63;
    const int g = lane >> 3;
    const int q = lane & 7;
    const int beg = rowptr[w];
    const int end = rowptr[w + 1];
    const float dn = dinv[w];
    const half8* A8 = (const half8*)A16;

    float4 a0 = make_float4(0.f, 0.f, 0.f, 0.f);
    float4 a1 = make_float4(0.f, 0.f, 0.f, 0.f);
    float4 a2 = make_float4(0.f, 0.f, 0.f, 0.f);
    float4 a3 = make_float4(0.f, 0.f, 0.f, 0.f);
    for (int e = beg + g; e < end; e += 8) {
        int2 ed = edges[e];
        int s = ed.x;
        float nrm = dn * __int_as_float(ed.y);
        half8 v0 = A8[(size_t)s * 16 + q * 2];
        half8 v1 = A8[(size_t)s * 16 + q * 2 + 1];
        a0.x = fmaf(nrm, (float)v0[0], a0.x); a0.y = fmaf(nrm, (float)v0[1], a0.y);
        a0.z = fmaf(nrm, (float)v0[2], a0.z); a0.w = fmaf(nrm, (float)v0[3], a0.w);
        a1.x = fmaf(nrm, (float)v0[4], a1.x); a1.y = fmaf(nrm, (float)v0[5], a1.y);
        a1.z = fmaf(nrm, (float)v0[6], a1.z); a1.w = fmaf(nrm, (float)v0[7], a1.w);
        a2.x = fmaf(nrm, (float)v1[0], a2.x); a2.y = fmaf(nrm, (float)v1[1], a2.y);
        a2.z = fmaf(nrm, (float)v1[2], a2.z); a2.w = fmaf(nrm, (float)v1[3], a2.w);
        a3.x = fmaf(nrm, (float)v1[4], a3.x); a3.y = fmaf(nrm, (float)v1[5], a3.y);
        a3.z = fmaf(nrm, (float)v1[6], a3.z); a3.w = fmaf(nrm, (float)v1[7], a3.w);
    }
    #pragma unroll
    for (int m = 8; m <= 32; m <<= 1) {
        a0.x += __shfl_xor(a0.x, m); a0.y += __shfl_xor(a0.y, m);
        a0.z += __shfl_xor(a0.z, m); a0.w += __shfl_xor(a0.w, m);
        a1.x += __shfl_xor(a1.x, m); a1.y += __shfl_xor(a1.y, m);
        a1.z += __shfl_xor(a1.z, m); a1.w += __shfl_xor(a1.w, m);
        a2.x += __shfl_xor(a2.x, m); a2.y += __shfl_xor(a2.y, m);
        a2.z += __shfl_xor(a2.z, m); a2.w += __shfl_xor(a2.w, m);
        a3.x += __shfl_xor(a3.x, m); a3.y += __shfl_xor(a3.y, m);
        a3.z += __shfl_xor(a3.z, m); a3.w += __shfl_xor(a3.w, m);
    }

    if (g == 0) {
        half8 s0 = A8[(size_t)w * 16 + q * 2];
        half8 s1 = A8[(size_t)w * 16 + q * 2 + 1];
        float4 b0 = ((const float4*)bias)[q * 4];
        float4 b1 = ((const float4*)bias)[q * 4 + 1];
        float4 b2 = ((const float4*)bias)[q * 4 + 2];
        float4 b3 = ((const float4*)bias)[q * 4 + 3];
        float d2 = dn * dn;
        half8 o0, o1;
        o0[0] = (_Float16)fmaxf(fmaf(d2, (float)s0[0], a0.x + b0.x), 0.f);
        o0[1] = (_Float16)fmaxf(fmaf(d2, (float)s0[1], a0.y + b0.y), 0.f);
        o0[2] = (_Float16)fmaxf(fmaf(d2, (float)s0[2], a0.z + b0.z), 0.f);
        o0[3] = (_Float16)fmaxf(fmaf(d2, (float)s0[3], a0.w + b0.w), 0.f);
        o0[4] = (_Float16)fmaxf(fmaf(d2, (float)s0[4], a1.x + b1.x), 0.f);
        o0[5] = (_Float16)fmaxf(fmaf(d2, (float)s0[5], a1.y + b1.y), 0.f);
        o0[6] = (_Float16)fmaxf(fmaf(d2, (float)s0[6], a1.z + b1.z), 0.f);
        o0[7] = (_Float16)fmaxf(fmaf(d2, (float)s0[7], a1.w + b1.w), 0.f);
        o1[0] = (_Float16)fmaxf(fmaf(d2, (float)s1[0], a2.x + b2.x), 0.f);
        o1[1] = (_Float16)fmaxf(fmaf(d2, (float)s1[1], a2.y + b2.y), 0.f);
        o1[2] = (_Float16)fmaxf(fmaf(d2, (float)s1[2], a2.z + b2.z), 0.f);
        o1[3] = (_Float16)fmaxf(fmaf(d2, (float)s1[3], a2.w + b2.w), 0.f);
        o1[4] = (_Float16)fmaxf(fmaf(d2, (float)s1[4], a3.x + b3.x), 0.f);
        o1[5] = (_Float16)fmaxf(fmaf(d2, (float)s1[5], a3.y + b3.y), 0.f);
        o1[6] = (_Float16)fmaxf(fmaf(d2, (float)s1[6], a3.z + b3.z), 0.f);
        o1[7] = (_Float16)fmaxf(fmaf(d2, (float)s1[7], a3.w + b3.w), 0.f);
        half8* Hp = (half8*)H16 + (size_t)w * 16 + q * 2;
        Hp[0] = o0;
        Hp[1] = o1;
    }
}

// layer-3 head: agg (8 edges in flight) then nodeval[n] = dot(relu(row), lin_w)
__global__ __launch_bounds__(256) void agg_head_kernel(const int* __restrict__ rowptr,
                                                       const int2* __restrict__ edges,
                                                       const float* __restrict__ dinv,
                                                       const _Float16* __restrict__ A16,
                                                       const float* __restrict__ bias,
                                                       const float* __restrict__ lin_w,
                                                       float* __restrict__ nodeval, int N) {
    int w = (blockIdx.x * 256 + threadIdx.x) >> 6;
    if (w >= N) return;
    const int lane = threadIdx.x & 63;
    const int g = lane >> 3;
    const int q = lane & 7;
    const int beg = rowptr[w];
    const int end = rowptr[w + 1];
    const float dn = dinv[w];
    const half8* A8 = (const half8*)A16;

    float4 a0 = make_float4(0.f, 0.f, 0.f, 0.f);
    float4 a1 = make_float4(0.f, 0.f, 0.f, 0.f);
    float4 a2 = make_float4(0.f, 0.f, 0.f, 0.f);
    float4 a3 = make_float4(0.f, 0.f, 0.f, 0.f);
    for (int e = beg + g; e < end; e += 8) {
        int2 ed = edges[e];
        int s = ed.x;
        float nrm = dn * __int_as_float(ed.y);
        half8 v0 = A8[(size_t)s * 16 + q * 2];
        half8 v1 = A8[(size_t)s * 16 + q * 2 + 1];
        a0.x = fmaf(nrm, (float)v0[0], a0.x); a0.y = fmaf(nrm, (float)v0[1], a0.y);
        a0.z = fmaf(nrm, (float)v0[2], a0.z); a0.w = fmaf(nrm, (float)v0[3], a0.w);
        a1.x = fmaf(nrm, (float)v0[4], a1.x); a1.y = fmaf(nrm, (float)v0[5], a1.y);
        a1.z = fmaf(nrm, (float)v0[6], a1.z); a1.w = fmaf(nrm, (float)v0[7], a1.w);
        a2.x = fmaf(nrm, (float)v1[0], a2.x); a2.y = fmaf(nrm, (float)v1[1], a2.y);
        a2.z = fmaf(nrm, (float)v1[2], a2.z); a2.w = fmaf(nrm, (float)v1[3], a2.w);
        a3.x = fmaf(nrm, (float)v1[4], a3.x); a3.y = fmaf(nrm, (float)v1[5], a3.y);
        a3.z = fmaf(nrm, (float)v1[6], a3.z); a3.w = fmaf(nrm, (float)v1[7], a3.w);
    }
    #pragma unroll
    for (int m = 8; m <= 32; m <<= 1) {
        a0.x += __shfl_xor(a0.x, m); a0.y += __shfl_xor(a0.y, m);
        a0.z += __shfl_xor(a0.z, m); a0.w += __shfl_xor(a0.w, m);
        a1.x += __shfl_xor(a1.x, m); a1.y += __shfl_xor(a1.y, m);
        a1.z += __shfl_xor(a1.z, m); a1.w += __shfl_xor(a1.w, m);
        a2.x += __shfl_xor(a2.x, m); a2.y += __shfl_xor(a2.y, m);
        a2.z += __shfl_xor(a2.z, m); a2.w += __shfl_xor(a2.w, m);
        a3.x += __shfl_xor(a3.x, m); a3.y += __shfl_xor(a3.y, m);
        a3.z += __shfl_xor(a3.z, m); a3.w += __shfl_xor(a3.w, m);
    }

    if (g == 0) {
        half8 s0 = A8[(size_t)w * 16 + q * 2];
        half8 s1 = A8[(size_t)w * 16 + q * 2 + 1];
        float4 b0 = ((const float4*)bias)[q * 4];
        float4 b1 = ((const float4*)bias)[q * 4 + 1];
        float4 b2 = ((const float4*)bias)[q * 4 + 2];
        float4 b3 = ((const float4*)bias)[q * 4 + 3];
        float d2 = dn * dn;
        a0.x = fmaf(d2, (float)s0[0], a0.x + b0.x);
        a0.y = fmaf(d2, (float)s0[1], a0.y + b0.y);
        a0.z = fmaf(d2, (float)s0[2], a0.z + b0.z);
        a0.w = fmaf(d2, (float)s0[3], a0.w + b0.w);
        a1.x = fmaf(d2, (float)s0[4], a1.x + b1.x);
        a1.y = fmaf(d2, (float)s0[5], a1.y + b1.y);
        a1.z = fmaf(d2, (float)s0[6], a1.z + b1.z);
        a1.w = fmaf(d2, (float)s0[7], a1.w + b1.w);
        a2.x = fmaf(d2, (float)s1[0], a2.x + b2.x);
        a2.y = fmaf(d2, (float)s1[1], a2.y + b2.y);
        a2.z = fmaf(d2, (float)s1[2], a2.z + b2.z);
        a2.w = fmaf(d2, (float)s1[3], a2.w + b2.w);
        a3.x = fmaf(d2, (float)s1[4], a3.x + b3.x);
        a3.y = fmaf(d2, (float)s1[5], a3.y + b3.y);
        a3.z = fmaf(d2, (float)s1[6], a3.z + b3.z);
        a3.w = fmaf(d2, (float)s1[7], a3.w + b3.w);
        float4 w0 = ((const float4*)lin_w)[q * 4];
        float4 w1 = ((const float4*)lin_w)[q * 4 + 1];
        float4 w2 = ((const float4*)lin_w)[q * 4 + 2];
        float4 w3 = ((const float4*)lin_w)[q * 4 + 3];
        float s = fmaxf(a0.x, 0.f) * w0.x + fmaxf(a0.y, 0.f) * w0.y
                + fmaxf(a0.z, 0.f) * w0.z + fmaxf(a0.w, 0.f) * w0.w
                + fmaxf(a1.x, 0.f) * w1.x + fmaxf(a1.y, 0.f) * w1.y
                + fmaxf(a1.z, 0.f) * w1.z + fmaxf(a1.w, 0.f) * w1.w
                + fmaxf(a2.x, 0.f) * w2.x + fmaxf(a2.y, 0.f) * w2.y
                + fmaxf(a2.z, 0.f) * w2.z + fmaxf(a2.w, 0.f) * w2.w
                + fmaxf(a3.x, 0.f) * w3.x + fmaxf(a3.y, 0.f) * w3.y
                + fmaxf(a3.z, 0.f) * w3.z + fmaxf(a3.w, 0.f) * w3.w;
        s += __shfl_xor(s, 1);
        s += __shfl_xor(s, 2);
        s += __shfl_xor(s, 4);
        if (q == 0) nodeval[w] = s;
    }
}

__device__ __forceinline__ int lower_bound_dev(const int* __restrict__ a, int n, int key) {
    int lo = 0, hi = n;
    while (lo < hi) {
        int mid = (lo + hi) >> 1;
        if (a[mid] < key) lo = mid + 1; else hi = mid;
    }
    return lo;
}

// one block per graph: out[g] = mean(nodeval[lo:hi]) + lin_b  (batch is sorted)
__global__ __launch_bounds__(256) void segreduce_kernel(const float* __restrict__ nodeval,
                                                        const int* __restrict__ batch,
                                                        const float* __restrict__ lin_b,
                                                        float* __restrict__ out, int N) {
    const int g = blockIdx.x;
    const int lo = lower_bound_dev(batch, N, g);
    const int hi = lower_bound_dev(batch, N, g + 1);
    float acc = 0.f;
    for (int n = lo + threadIdx.x; n < hi; n += 256) acc += nodeval[n];
    __shared__ float red[256];
    red[threadIdx.x] = acc;
    __syncthreads();
    for (int s = 128; s > 0; s >>= 1) {
        if (threadIdx.x < s) red[threadIdx.x] += red[threadIdx.x + s];
        __syncthreads();
    }
    if (threadIdx.x == 0) {
        float cnt = (float)(hi - lo);
        out[g] = red[0] / fmaxf(cnt, 1.0f) + lin_b[0];
    }
}

extern "C" void kernel_launch(void* const* d_in, const int* in_sizes, int n_in,
                              void* d_out, int out_size, void* d_ws, size_t ws_size,
                              hipStream_t stream) {
    const float* x     = (const float*)d_in[0];
    const int*   ei    = (const int*)d_in[1];    // [2,E]: rows then cols
    const int*   batch = (const int*)d_in[2];
    const float* W1    = (const float*)d_in[3];
    const float* b1    = (const float*)d_in[4];
    const float* W2    = (const float*)d_in[5];
    const float* b2    = (const float*)d_in[6];
    const float* W3    = (const float*)d_in[7];
    const float* b3    = (const float*)d_in[8];
    const float* lin_w = (const float*)d_in[9];
    const float* lin_b = (const float*)d_in[10];
    float* out = (float*)d_out;

    const int N = in_sizes[0] / 128;
    const int E = in_sizes[1] / 2;
    const int nBlk = (N + 1023) / 1024;
    const int npb = (N + 63) / 64;               // nodes per bucket (64 buckets)
    const int eChunks = (E + P1_EDGES - 1) / P1_EDGES;

    // workspace layout (8B-alignment preserved across int2 arrays)
    _Float16* A16    = (_Float16*)d_ws;                       // N*128
    _Float16* H16    = A16 + (size_t)N * 128;                 // N*128
    int*   deg       = (int*)(H16 + (size_t)N * 128);         // N
    int*   bucketCnt8= deg + N;                               // 512
    int*   bucketStart=bucketCnt8 + 512;                      // 64
    int*   bucketTail= bucketStart + 64;                      // 64
    float* dinv      = (float*)(bucketTail + 64);             // N
    int*   rowptr    = (int*)(dinv + N);                      // N+2 (pad for align)
    int*   nodeTail  = rowptr + N + 2;                        // N
    int2*  edges     = (int2*)(nodeTail + N);                 // E
    int2*  tmp       = edges + E;                             // E
    int*   blockSums = (int*)(tmp + E);                       // 256
    int*   blockOffs = blockSums + 256;                       // 256
    float* nodeval   = (float*)(blockOffs + 256);             // N
    _Float16* W16    = (_Float16*)(nodeval + N);              // 3*16384

    // ---- radix two-pass CSR build ----
    hipMemsetAsync(deg, 0, (size_t)(N + 512) * sizeof(int), stream);  // deg + bucketCnt8
    hist_kernel<<<eChunks, 256, 0, stream>>>(ei + E, bucketCnt8, E, npb);
    bucketscan_kernel<<<1, 64, 0, stream>>>(bucketCnt8, bucketStart, bucketTail);
    pass1_kernel<<<8 * eChunks, 256, 0, stream>>>(ei, deg, bucketTail, tmp, E, npb);
    scan1_kernel<<<nBlk, 256, 0, stream>>>(deg, rowptr, dinv, blockSums, N);
    scan2_kernel<<<1, 128, 0, stream>>>(blockSums, blockOffs, nBlk);
    scan3_kernel<<<(N + 255) / 256, 256, 0, stream>>>(rowptr, nodeTail, blockOffs, N, E);
    pass2_kernel<<<8 * 8 * P2_SUBS, 256, 0, stream>>>(tmp, bucketStart, bucketTail,
                                                      dinv, nodeTail, edges);
    wcast_kernel<<<192, 256, 0, stream>>>(W1, W2, W3, W16);

    const int gBlocks = (N + 63) / 64;
    const int aBlocks = ((size_t)N * 64 + 255) / 256;

    // layer 1: x @ W1 -> A16 ; agg -> H16 (relu fp16)
    gemm_f32_kernel<<<gBlocks, 256, 0, stream>>>(x, W16, A16, N);
    agg_kernel<<<aBlocks, 256, 0, stream>>>(rowptr, edges, dinv, A16, b1, H16, N);
    // layer 2: H16 @ W2 -> A16 ; agg -> H16
    gemm_f16_kernel<<<gBlocks, 256, 0, stream>>>(H16, W16 + 16384, A16, N);
    agg_kernel<<<aBlocks, 256, 0, stream>>>(rowptr, edges, dinv, A16, b2, H16, N);
    // layer 3: H16 @ W3 -> A16 ; head agg + dot -> nodeval
    gemm_f16_kernel<<<gBlocks, 256, 0, stream>>>(H16, W16 + 32768, A16, N);
    agg_head_kernel<<<aBlocks, 256, 0, stream>>>(rowptr, edges, dinv,
                                                 A16, b3, lin_w, nodeval, N);
    segreduce_kernel<<<64, 256, 0, stream>>>(nodeval, batch, lin_b, out, N);
}

// Round 14
// 513.581 us; speedup vs baseline: 1.1057x; 1.1057x over previous
//
#include <hip/hip_runtime.h>

// ---------------------------------------------------------------------------
// GCN forward (R12 build revert + independent-kernel merges):
//   prep:   [wcast | count_deg] one launch (independent work co-scheduled)
//   build:  scan1(+dinv) -> scan2 -> scan3 -> [gemm1 | fill] one launch
//   layer2: H16 @ W2 -> A16 ; agg -> H16
//   layer3: H16 @ W3 -> A16 ; head agg + lin_w dot -> nodeval -> segreduce
// edges[pos] = {src, dinv[src]} int2; agg: 8 lanes/edge x 32B, 8 edges in flight.
// ---------------------------------------------------------------------------

typedef __attribute__((ext_vector_type(4))) float f32x4;
typedef __attribute__((ext_vector_type(8))) _Float16 half8;

// ---- device helpers -------------------------------------------------------

__device__ __forceinline__ void gemm_f32_body(const float* __restrict__ H,
                                              const _Float16* __restrict__ W16,
                                              _Float16* __restrict__ T16,
                                              int N, int bid) {
    const int tid = threadIdx.x;
    const int wv = tid >> 6;
    const int lane = tid & 63;
    const int r0 = bid * 64 + wv * 16;
    const int mrow = lane & 15;
    const int kq = lane >> 4;
    const int grow = r0 + mrow;
    const bool rok = grow < N;

    f32x4 acc[8];
    #pragma unroll
    for (int t = 0; t < 8; ++t) acc[t] = (f32x4){0.f, 0.f, 0.f, 0.f};

    #pragma unroll
    for (int c = 0; c < 4; ++c) {
        half8 a = (half8)(_Float16)0;
        if (rok) {
            const float4* Hp = (const float4*)(H + (size_t)grow * 128 + c * 32 + kq * 8);
            float4 a0 = Hp[0], a1 = Hp[1];
            a[0] = (_Float16)a0.x; a[1] = (_Float16)a0.y;
            a[2] = (_Float16)a0.z; a[3] = (_Float16)a0.w;
            a[4] = (_Float16)a1.x; a[5] = (_Float16)a1.y;
            a[6] = (_Float16)a1.z; a[7] = (_Float16)a1.w;
        }
        #pragma unroll
        for (int t = 0; t < 8; ++t) {
            half8 w = *(const half8*)&W16[(((c * 8 + t) * 64) + lane) * 8];
            acc[t] = __builtin_amdgcn_mfma_f32_16x16x32_f16(a, w, acc[t], 0, 0, 0);
        }
    }
    #pragma unroll
    for (int r = 0; r < 4; ++r) {
        int orow = r0 + kq * 4 + r;
        if (orow < N) {
            _Float16* Tp = T16 + (size_t)orow * 128 + mrow;
            #pragma unroll
            for (int t = 0; t < 8; ++t) Tp[t * 16] = (_Float16)acc[t][r];
        }
    }
}

// ---- merged launch 1: wcast (192 blocks) | count_deg (rest) ---------------
// wcast: all three W[128][128] fp32 -> fp16 in MFMA B-fragment order
//   idx = ((c*8+t)*64+lane)*8+j <-> W[k][n], k=c*32+(lane>>4)*8+j, n=t*16+(lane&15)
// count_deg: XCD-partitioned (8 blocks round-robin share each edge chunk)
__global__ __launch_bounds__(256) void prep_kernel(const float* __restrict__ W1,
                                                   const float* __restrict__ W2,
                                                   const float* __restrict__ W3,
                                                   _Float16* __restrict__ W16,
                                                   const int* __restrict__ col,
                                                   int* __restrict__ deg,
                                                   int E, int partSize) {
    if (blockIdx.x < 192) {
        int layer = blockIdx.x >> 6;
        const float* W = (layer == 0) ? W1 : (layer == 1) ? W2 : W3;
        _Float16* Wd = W16 + layer * 16384;
        int i = (blockIdx.x & 63) * 256 + threadIdx.x;
        int j = i & 7;
        int l = (i >> 3) & 63;
        int t = (i >> 9) & 7;
        int c = i >> 12;
        int k = c * 32 + (l >> 4) * 8 + j;
        int n = t * 16 + (l & 15);
        Wd[i] = (_Float16)W[k * 128 + n];
    } else {
        int bid = blockIdx.x - 192;           // 192 % 8 == 0: p<->XCD mapping kept
        const int p = bid & 7;
        const int e = (bid >> 3) * 256 + threadIdx.x;
        if (e >= E) return;
        int c = col[e];
        if (c / partSize == p) atomicAdd(&deg[c], 1);
    }
}

// per-block exclusive scan of deg (1024/block) -> rowptr; also dinv = rsqrt(deg+1)
__global__ __launch_bounds__(256) void scan1_kernel(const int* __restrict__ deg,
                                                    int* __restrict__ rowptr,
                                                    float* __restrict__ dinv,
                                                    int* __restrict__ blockSums, int N) {
    __shared__ int ts[256];
    const int t = threadIdx.x;
    const int base = blockIdx.x * 1024 + t * 4;
    int v0 = 0, v1 = 0, v2 = 0, v3 = 0;
    if (base + 3 < N) {
        int4 v = *(const int4*)&deg[base];
        v0 = v.x; v1 = v.y; v2 = v.z; v3 = v.w;
    } else {
        if (base + 0 < N) v0 = deg[base + 0];
        if (base + 1 < N) v1 = deg[base + 1];
        if (base + 2 < N) v2 = deg[base + 2];
        if (base + 3 < N) v3 = deg[base + 3];
    }
    if (base + 0 < N) dinv[base + 0] = 1.0f / sqrtf((float)v0 + 1.0f);
    if (base + 1 < N) dinv[base + 1] = 1.0f / sqrtf((float)v1 + 1.0f);
    if (base + 2 < N) dinv[base + 2] = 1.0f / sqrtf((float)v2 + 1.0f);
    if (base + 3 < N) dinv[base + 3] = 1.0f / sqrtf((float)v3 + 1.0f);
    const int tot = v0 + v1 + v2 + v3;
    ts[t] = tot;
    __syncthreads();
    for (int off = 1; off < 256; off <<= 1) {
        int add = (t >= off) ? ts[t - off] : 0;
        __syncthreads();
        ts[t] += add;
        __syncthreads();
    }
    const int excl = ts[t] - tot;
    if (base + 0 < N) rowptr[base + 0] = excl;
    if (base + 1 < N) rowptr[base + 1] = excl + v0;
    if (base + 2 < N) rowptr[base + 2] = excl + v0 + v1;
    if (base + 3 < N) rowptr[base + 3] = excl + v0 + v1 + v2;
    if (t == 255) blockSums[blockIdx.x] = ts[255];
}

__global__ __launch_bounds__(128) void scan2_kernel(const int* __restrict__ blockSums,
                                                    int* __restrict__ blockOffs, int B) {
    __shared__ int ts[128];
    const int t = threadIdx.x;
    ts[t] = (t < B) ? blockSums[t] : 0;
    __syncthreads();
    for (int off = 1; off < 128; off <<= 1) {
        int add = (t >= off) ? ts[t - off] : 0;
        __syncthreads();
        ts[t] += add;
        __syncthreads();
    }
    if (t < B) blockOffs[t] = ts[t];
}

__global__ __launch_bounds__(256) void scan3_kernel(int* __restrict__ rowptr,
                                                    const int* __restrict__ blockOffs, int N) {
    int i = blockIdx.x * 256 + threadIdx.x;
    if (i >= N) return;
    int b = i >> 10;
    if (b > 0) rowptr[i] += blockOffs[b - 1];
}

// ---- merged launch 2: gemm1 (gBlocks) | fill (rest) -----------------------
// fill: XCD-partitioned counting-sort (rowptr-shift trick); one int2 scatter/edge.
// gemm1 is independent of the CSR build; co-scheduled to fill fill's idle pipes.
__global__ __launch_bounds__(256) void fill_gemm1_kernel(
        const float* __restrict__ x, const _Float16* __restrict__ W16,
        _Float16* __restrict__ A16, int N, int gBlocks,
        const int* __restrict__ ei, const float* __restrict__ dinv,
        int* __restrict__ rowptr, int2* __restrict__ edges, int E, int partSize) {
    if ((int)blockIdx.x < gBlocks) {
        gemm_f32_body(x, W16, A16, N, blockIdx.x);
    } else {
        int bid = blockIdx.x - gBlocks;
        const int p = bid & 7;                // consistent p<->XCD shift (bijection)
        const int e = (bid >> 3) * 256 + threadIdx.x;
        if (e >= E) return;
        int c = ei[E + e];
        if (c / partSize != p) return;
        int r = ei[e];
        int pos = atomicAdd(&rowptr[c], 1);
        edges[pos] = make_int2(r, __float_as_int(dinv[r]));
    }
}

// A16 = fp16( H16 @ W16 ) via f16 MFMA (layers 2/3)
__global__ __launch_bounds__(256) void gemm_f16_kernel(const _Float16* __restrict__ H16,
                                                       const _Float16* __restrict__ W16,
                                                       _Float16* __restrict__ T16,
                                                       int N) {
    const int tid = threadIdx.x;
    const int wv = tid >> 6;
    const int lane = tid & 63;
    const int r0 = blockIdx.x * 64 + wv * 16;
    const int mrow = lane & 15;
    const int kq = lane >> 4;
    const int grow = r0 + mrow;
    const bool rok = grow < N;

    f32x4 acc[8];
    #pragma unroll
    for (int t = 0; t < 8; ++t) acc[t] = (f32x4){0.f, 0.f, 0.f, 0.f};

    #pragma unroll
    for (int c = 0; c < 4; ++c) {
        half8 a = (half8)(_Float16)0;
        if (rok) a = *(const half8*)(H16 + (size_t)grow * 128 + c * 32 + kq * 8);
        #pragma unroll
        for (int t = 0; t < 8; ++t) {
            half8 w = *(const half8*)&W16[(((c * 8 + t) * 64) + lane) * 8];
            acc[t] = __builtin_amdgcn_mfma_f32_16x16x32_f16(a, w, acc[t], 0, 0, 0);
        }
    }
    #pragma unroll
    for (int r = 0; r < 4; ++r) {
        int orow = r0 + kq * 4 + r;
        if (orow < N) {
            _Float16* Tp = T16 + (size_t)orow * 128 + mrow;
            #pragma unroll
            for (int t = 0; t < 8; ++t) Tp[t * 16] = (_Float16)acc[t][r];
        }
    }
}

// one wave per node; 8 lanes/edge x 32B (2 x half8), 8 edges in flight.
// H16[n,:] = fp16(relu( dinv[n]^2*A[n,:] + bias + sum_e dn*w_e*A[src_e,:] ))
// NOTE: fill advanced rowptr; bucket w = [w==0?0:rowptr[w-1], rowptr[w])
__global__ __launch_bounds__(256) void agg_kernel(const int* __restrict__ rowptr,
                                                  const int2* __restrict__ edges,
                                                  const float* __restrict__ dinv,
                                                  const _Float16* __restrict__ A16,
                                                  const float* __restrict__ bias,
                                                  _Float16* __restrict__ H16, int N) {
    int w = (blockIdx.x * 256 + threadIdx.x) >> 6;
    if (w >= N) return;
    const int lane = threadIdx.x & 63;
    const int g = lane >> 3;
    const int q = lane & 7;
    const int beg = (w > 0) ? rowptr[w - 1] : 0;
    const int end = rowptr[w];
    const float dn = dinv[w];
    const half8* A8 = (const half8*)A16;

    float4 a0 = make_float4(0.f, 0.f, 0.f, 0.f);
    float4 a1 = make_float4(0.f, 0.f, 0.f, 0.f);
    float4 a2 = make_float4(0.f, 0.f, 0.f, 0.f);
    float4 a3 = make_float4(0.f, 0.f, 0.f, 0.f);
    for (int e = beg + g; e < end; e += 8) {
        int2 ed = edges[e];
        int s = ed.x;
        float nrm = dn * __int_as_float(ed.y);
        half8 v0 = A8[(size_t)s * 16 + q * 2];
        half8 v1 = A8[(size_t)s * 16 + q * 2 + 1];
        a0.x = fmaf(nrm, (float)v0[0], a0.x); a0.y = fmaf(nrm, (float)v0[1], a0.y);
        a0.z = fmaf(nrm, (float)v0[2], a0.z); a0.w = fmaf(nrm, (float)v0[3], a0.w);
        a1.x = fmaf(nrm, (float)v0[4], a1.x); a1.y = fmaf(nrm, (float)v0[5], a1.y);
        a1.z = fmaf(nrm, (float)v0[6], a1.z); a1.w = fmaf(nrm, (float)v0[7], a1.w);
        a2.x = fmaf(nrm, (float)v1[0], a2.x); a2.y = fmaf(nrm, (float)v1[1], a2.y);
        a2.z = fmaf(nrm, (float)v1[2], a2.z); a2.w = fmaf(nrm, (float)v1[3], a2.w);
        a3.x = fmaf(nrm, (float)v1[4], a3.x); a3.y = fmaf(nrm, (float)v1[5], a3.y);
        a3.z = fmaf(nrm, (float)v1[6], a3.z); a3.w = fmaf(nrm, (float)v1[7], a3.w);
    }
    #pragma unroll
    for (int m = 8; m <= 32; m <<= 1) {
        a0.x += __shfl_xor(a0.x, m); a0.y += __shfl_xor(a0.y, m);
        a0.z += __shfl_xor(a0.z, m); a0.w += __shfl_xor(a0.w, m);
        a1.x += __shfl_xor(a1.x, m); a1.y += __shfl_xor(a1.y, m);
        a1.z += __shfl_xor(a1.z, m); a1.w += __shfl_xor(a1.w, m);
        a2.x += __shfl_xor(a2.x, m); a2.y += __shfl_xor(a2.y, m);
        a2.z += __shfl_xor(a2.z, m); a2.w += __shfl_xor(a2.w, m);
        a3.x += __shfl_xor(a3.x, m); a3.y += __shfl_xor(a3.y, m);
        a3.z += __shfl_xor(a3.z, m); a3.w += __shfl_xor(a3.w, m);
    }

    if (g == 0) {
        half8 s0 = A8[(size_t)w * 16 + q * 2];
        half8 s1 = A8[(size_t)w * 16 + q * 2 + 1];
        float4 b0 = ((const float4*)bias)[q * 4];
        float4 b1 = ((const float4*)bias)[q * 4 + 1];
        float4 b2 = ((const float4*)bias)[q * 4 + 2];
        float4 b3 = ((const float4*)bias)[q * 4 + 3];
        float d2 = dn * dn;
        half8 o0, o1;
        o0[0] = (_Float16)fmaxf(fmaf(d2, (float)s0[0], a0.x + b0.x), 0.f);
        o0[1] = (_Float16)fmaxf(fmaf(d2, (float)s0[1], a0.y + b0.y), 0.f);
        o0[2] = (_Float16)fmaxf(fmaf(d2, (float)s0[2], a0.z + b0.z), 0.f);
        o0[3] = (_Float16)fmaxf(fmaf(d2, (float)s0[3], a0.w + b0.w), 0.f);
        o0[4] = (_Float16)fmaxf(fmaf(d2, (float)s0[4], a1.x + b1.x), 0.f);
        o0[5] = (_Float16)fmaxf(fmaf(d2, (float)s0[5], a1.y + b1.y), 0.f);
        o0[6] = (_Float16)fmaxf(fmaf(d2, (float)s0[6], a1.z + b1.z), 0.f);
        o0[7] = (_Float16)fmaxf(fmaf(d2, (float)s0[7], a1.w + b1.w), 0.f);
        o1[0] = (_Float16)fmaxf(fmaf(d2, (float)s1[0], a2.x + b2.x), 0.f);
        o1[1] = (_Float16)fmaxf(fmaf(d2, (float)s1[1], a2.y + b2.y), 0.f);
        o1[2] = (_Float16)fmaxf(fmaf(d2, (float)s1[2], a2.z + b2.z), 0.f);
        o1[3] = (_Float16)fmaxf(fmaf(d2, (float)s1[3], a2.w + b2.w), 0.f);
        o1[4] = (_Float16)fmaxf(fmaf(d2, (float)s1[4], a3.x + b3.x), 0.f);
        o1[5] = (_Float16)fmaxf(fmaf(d2, (float)s1[5], a3.y + b3.y), 0.f);
        o1[6] = (_Float16)fmaxf(fmaf(d2, (float)s1[6], a3.z + b3.z), 0.f);
        o1[7] = (_Float16)fmaxf(fmaf(d2, (float)s1[7], a3.w + b3.w), 0.f);
        half8* Hp = (half8*)H16 + (size_t)w * 16 + q * 2;
        Hp[0] = o0;
        Hp[1] = o1;
    }
}

// layer-3 head: agg (8 edges in flight) then nodeval[n] = dot(relu(row), lin_w)
__global__ __launch_bounds__(256) void agg_head_kernel(const int* __restrict__ rowptr,
                                                       const int2* __restrict__ edges,
                                                       const float* __restrict__ dinv,
                                                       const _Float16* __restrict__ A16,
                                                       const float* __restrict__ bias,
                                                       const float* __restrict__ lin_w,
                                                       float* __restrict__ nodeval, int N) {
    int w = (blockIdx.x * 256 + threadIdx.x) >> 6;
    if (w >= N) return;
    const int lane = threadIdx.x & 63;
    const int g = lane >> 3;
    const int q = lane & 7;
    const int beg = (w > 0) ? rowptr[w - 1] : 0;
    const int end = rowptr[w];
    const float dn = dinv[w];
    const half8* A8 = (const half8*)A16;

    float4 a0 = make_float4(0.f, 0.f, 0.f, 0.f);
    float4 a1 = make_float4(0.f, 0.f, 0.f, 0.f);
    float4 a2 = make_float4(0.f, 0.f, 0.f, 0.f);
    float4 a3 = make_float4(0.f, 0.f, 0.f, 0.f);
    for (int e = beg + g; e < end; e += 8) {
        int2 ed = edges[e];
        int s = ed.x;
        float nrm = dn * __int_as_float(ed.y);
        half8 v0 = A8[(size_t)s * 16 + q * 2];
        half8 v1 = A8[(size_t)s * 16 + q * 2 + 1];
        a0.x = fmaf(nrm, (float)v0[0], a0.x); a0.y = fmaf(nrm, (float)v0[1], a0.y);
        a0.z = fmaf(nrm, (float)v0[2], a0.z); a0.w = fmaf(nrm, (float)v0[3], a0.w);
        a1.x = fmaf(nrm, (float)v0[4], a1.x); a1.y = fmaf(nrm, (float)v0[5], a1.y);
        a1.z = fmaf(nrm, (float)v0[6], a1.z); a1.w = fmaf(nrm, (float)v0[7], a1.w);
        a2.x = fmaf(nrm, (float)v1[0], a2.x); a2.y = fmaf(nrm, (float)v1[1], a2.y);
        a2.z = fmaf(nrm, (float)v1[2], a2.z); a2.w = fmaf(nrm, (float)v1[3], a2.w);
        a3.x = fmaf(nrm, (float)v1[4], a3.x); a3.y = fmaf(nrm, (float)v1[5], a3.y);
        a3.z = fmaf(nrm, (float)v1[6], a3.z); a3.w = fmaf(nrm, (float)v1[7], a3.w);
    }
    #pragma unroll
    for (int m = 8; m <= 32; m <<= 1) {
        a0.x += __shfl_xor(a0.x, m); a0.y += __shfl_xor(a0.y, m);
        a0.z += __shfl_xor(a0.z, m); a0.w += __shfl_xor(a0.w, m);
        a1.x += __shfl_xor(a1.x, m); a1.y += __shfl_xor(a1.y, m);
        a1.z += __shfl_xor(a1.z, m); a1.w += __shfl_xor(a1.w, m);
        a2.x += __shfl_xor(a2.x, m); a2.y += __shfl_xor(a2.y, m);
        a2.z += __shfl_xor(a2.z, m); a2.w += __shfl_xor(a2.w, m);
        a3.x += __shfl_xor(a3.x, m); a3.y += __shfl_xor(a3.y, m);
        a3.z += __shfl_xor(a3.z, m); a3.w += __shfl_xor(a3.w, m);
    }

    if (g == 0) {
        half8 s0 = A8[(size_t)w * 16 + q * 2];
        half8 s1 = A8[(size_t)w * 16 + q * 2 + 1];
        float4 b0 = ((const float4*)bias)[q * 4];
        float4 b1 = ((const float4*)bias)[q * 4 + 1];
        float4 b2 = ((const float4*)bias)[q * 4 + 2];
        float4 b3 = ((const float4*)bias)[q * 4 + 3];
        float d2 = dn * dn;
        a0.x = fmaf(d2, (float)s0[0], a0.x + b0.x);
        a0.y = fmaf(d2, (float)s0[1], a0.y + b0.y);
        a0.z = fmaf(d2, (float)s0[2], a0.z + b0.z);
        a0.w = fmaf(d2, (float)s0[3], a0.w + b0.w);
        a1.x = fmaf(d2, (float)s0[4], a1.x + b1.x);
        a1.y = fmaf(d2, (float)s0[5], a1.y + b1.y);
        a1.z = fmaf(d2, (float)s0[6], a1.z + b1.z);
        a1.w = fmaf(d2, (float)s0[7], a1.w + b1.w);
        a2.x = fmaf(d2, (float)s1[0], a2.x + b2.x);
        a2.y = fmaf(d2, (float)s1[1], a2.y + b2.y);
        a2.z = fmaf(d2, (float)s1[2], a2.z + b2.z);
        a2.w = fmaf(d2, (float)s1[3], a2.w + b2.w);
        a3.x = fmaf(d2, (float)s1[4], a3.x + b3.x);
        a3.y = fmaf(d2, (float)s1[5], a3.y + b3.y);
        a3.z = fmaf(d2, (float)s1[6], a3.z + b3.z);
        a3.w = fmaf(d2, (float)s1[7], a3.w + b3.w);
        float4 w0 = ((const float4*)lin_w)[q * 4];
        float4 w1 = ((const float4*)lin_w)[q * 4 + 1];
        float4 w2 = ((const float4*)lin_w)[q * 4 + 2];
        float4 w3 = ((const float4*)lin_w)[q * 4 + 3];
        float s = fmaxf(a0.x, 0.f) * w0.x + fmaxf(a0.y, 0.f) * w0.y
                + fmaxf(a0.z, 0.f) * w0.z + fmaxf(a0.w, 0.f) * w0.w
                + fmaxf(a1.x, 0.f) * w1.x + fmaxf(a1.y, 0.f) * w1.y
                + fmaxf(a1.z, 0.f) * w1.z + fmaxf(a1.w, 0.f) * w1.w
                + fmaxf(a2.x, 0.f) * w2.x + fmaxf(a2.y, 0.f) * w2.y
                + fmaxf(a2.z, 0.f) * w2.z + fmaxf(a2.w, 0.f) * w2.w
                + fmaxf(a3.x, 0.f) * w3.x + fmaxf(a3.y, 0.f) * w3.y
                + fmaxf(a3.z, 0.f) * w3.z + fmaxf(a3.w, 0.f) * w3.w;
        s += __shfl_xor(s, 1);
        s += __shfl_xor(s, 2);
        s += __shfl_xor(s, 4);
        if (q == 0) nodeval[w] = s;
    }
}

__device__ __forceinline__ int lower_bound_dev(const int* __restrict__ a, int n, int key) {
    int lo = 0, hi = n;
    while (lo < hi) {
        int mid = (lo + hi) >> 1;
        if (a[mid] < key) lo = mid + 1; else hi = mid;
    }
    return lo;
}

// one block per graph: out[g] = mean(nodeval[lo:hi]) + lin_b  (batch is sorted)
__global__ __launch_bounds__(256) void segreduce_kernel(const float* __restrict__ nodeval,
                                                        const int* __restrict__ batch,
                                                        const float* __restrict__ lin_b,
                                                        float* __restrict__ out, int N) {
    const int g = blockIdx.x;
    const int lo = lower_bound_dev(batch, N, g);
    const int hi = lower_bound_dev(batch, N, g + 1);
    float acc = 0.f;
    for (int n = lo + threadIdx.x; n < hi; n += 256) acc += nodeval[n];
    __shared__ float red[256];
    red[threadIdx.x] = acc;
    __syncthreads();
    for (int s = 128; s > 0; s >>= 1) {
        if (threadIdx.x < s) red[threadIdx.x] += red[threadIdx.x + s];
        __syncthreads();
    }
    if (threadIdx.x == 0) {
        float cnt = (float)(hi - lo);
        out[g] = red[0] / fmaxf(cnt, 1.0f) + lin_b[0];
    }
}

extern "C" void kernel_launch(void* const* d_in, const int* in_sizes, int n_in,
                              void* d_out, int out_size, void* d_ws, size_t ws_size,
                              hipStream_t stream) {
    const float* x     = (const float*)d_in[0];
    const int*   ei    = (const int*)d_in[1];    // [2,E]: rows then cols
    const int*   batch = (const int*)d_in[2];
    const float* W1    = (const float*)d_in[3];
    const float* b1    = (const float*)d_in[4];
    const float* W2    = (const float*)d_in[5];
    const float* b2    = (const float*)d_in[6];
    const float* W3    = (const float*)d_in[7];
    const float* b3    = (const float*)d_in[8];
    const float* lin_w = (const float*)d_in[9];
    const float* lin_b = (const float*)d_in[10];
    float* out = (float*)d_out;

    const int N = in_sizes[0] / 128;
    const int E = in_sizes[1] / 2;
    const int nBlk = (N + 1023) / 1024;
    const int partSize = (N + 7) / 8;            // XCD destination partition
    const int eChunks = (E + 255) / 256;
    const int gBlocks = (N + 63) / 64;
    const int aBlocks = ((size_t)N * 64 + 255) / 256;

    // workspace: A16 | H16 | deg | dinv | rowptr | edges(int2) | scan | nodeval | W16
    _Float16* A16    = (_Float16*)d_ws;
    _Float16* H16    = A16 + (size_t)N * 128;
    int*   deg       = (int*)(H16 + (size_t)N * 128);
    float* dinv      = (float*)(deg + N);
    int*   rowptr    = (int*)(dinv + N);
    int2*  edges     = (int2*)(rowptr + N);
    int*   blockSums = (int*)(edges + E);
    int*   blockOffs = blockSums + 256;
    float* nodeval   = (float*)(blockOffs + 256);
    _Float16* W16    = (_Float16*)(nodeval + N);   // 3 x 16384 fp16 fragments

    // ---- CSR build + layer-1 GEMM (overlapped) ----
    hipMemsetAsync(deg, 0, (size_t)N * sizeof(int), stream);
    prep_kernel<<<192 + 8 * eChunks, 256, 0, stream>>>(W1, W2, W3, W16,
                                                       ei + E, deg, E, partSize);
    scan1_kernel<<<nBlk, 256, 0, stream>>>(deg, rowptr, dinv, blockSums, N);
    scan2_kernel<<<1, 128, 0, stream>>>(blockSums, blockOffs, nBlk);
    scan3_kernel<<<(N + 255) / 256, 256, 0, stream>>>(rowptr, blockOffs, N);
    // gemm1 (x @ W1 -> A16) is independent of the CSR fill: one co-scheduled launch
    fill_gemm1_kernel<<<gBlocks + 8 * eChunks, 256, 0, stream>>>(
        x, W16, A16, N, gBlocks, ei, dinv, rowptr, edges, E, partSize);

    // layer 1 agg -> H16 (relu fp16)
    agg_kernel<<<aBlocks, 256, 0, stream>>>(rowptr, edges, dinv, A16, b1, H16, N);
    // layer 2: H16 @ W2 -> A16 ; agg -> H16
    gemm_f16_kernel<<<gBlocks, 256, 0, stream>>>(H16, W16 + 16384, A16, N);
    agg_kernel<<<aBlocks, 256, 0, stream>>>(rowptr, edges, dinv, A16, b2, H16, N);
    // layer 3: H16 @ W3 -> A16 ; head agg + dot -> nodeval
    gemm_f16_kernel<<<gBlocks, 256, 0, stream>>>(H16, W16 + 32768, A16, N);
    agg_head_kernel<<<aBlocks, 256, 0, stream>>>(rowptr, edges, dinv,
                                                 A16, b3, lin_w, nodeval, N);
    segreduce_kernel<<<64, 256, 0, stream>>>(nodeval, batch, lin_b, out, N);
}